// Round 7
// baseline (228.850 us; speedup 1.0000x reference)
//
#include <hip/hip_runtime.h>

// LinearCRF: mean_b( logZ_b - gold_b ), B=8192, L=1024, S=3.
// R7: two-kernel chunk decomposition, LANE = SEQUENCE.
//   Kernel A: grid = 64 seq-groups x 8 time-chunks (128 steps). Each lane
//   scans its own sequence's chunk sequentially (3x3 transfer-matrix product
//   in linear domain, exact pow2 renorm every 8 steps). NO cross-lane ops,
//   no scan butterflies (R4-R6's LDS-pipe + VALU tax). Inputs staged in
//   4-step subtiles through a small padded per-wave LDS region; all global
//   loads coalesced f4 (fixes R1-R3's 64-granule-per-instr L2 amplification).
//   Live set designed ~58 VGPRs: compiler pins this kernel family at ~64
//   (R1/R4/R5/R6 all spilled scratch above that; WRITE_SIZE is the tell).
//   Kernel B: 8192 lanes chain the 8 chunk matrices (alpha . P), add gold
//   boundary transitions, block-reduce, atomicAdd.

#define LOG2E 1.4426950408889634f
#define LN2   0.6931471805599453f

constexpr int B = 8192;
constexpr int NCHUNK = 8;
constexpr int NSUB = 32;      // 32 subtiles x 4 steps = 128-step chunk
constexpr int EM_ST = 14;     // LDS dwords/seq-row: 12 em + 2 pad (even->b64)
constexpr int MK_ST = 6;      // 4 + 2 pad
constexpr int TG_ST = 6;
constexpr int NF = 13;        // ws fields per chunk: P[9],scale,gold,m0,tagpack

__device__ __forceinline__ float fexp2(float x){ return __builtin_amdgcn_exp2f(x); }
__device__ __forceinline__ float flog2(float x){ return __builtin_amdgcn_logf(x); }
__device__ __forceinline__ float mux3(float a,float b,float c,int i){
  return i==0 ? a : (i==1 ? b : c);
}
__device__ __forceinline__ float trmux(const float* __restrict__ T2,int p,int c){
  const float r0 = mux3(T2[0],T2[1],T2[2],c);
  const float r1 = mux3(T2[3],T2[4],T2[5],c);
  const float r2 = mux3(T2[6],T2[7],T2[8],c);
  return mux3(r0,r1,r2,p);
}

// P <- P * M, column-wise (M never fully materialized).
// M col j = act ? tk[:,j]*w_j : e_j  (g = act?1:0, c1 = 1-g).
__device__ __forceinline__ void stepP(float* __restrict__ P,
                                      const float* __restrict__ tk,
                                      float w0, float w1, float w2, float g){
  const float c1 = 1.f - g;
  const float u0 = w0*g, u1 = w1*g, u2 = w2*g;
  float N0,N1,N2,N3,N4,N5,N6,N7,N8;
  { const float m0=fmaf(tk[0],u0,c1), m1=tk[3]*u0, m2=tk[6]*u0;
    N0 = P[0]*m0 + P[1]*m1 + P[2]*m2;
    N3 = P[3]*m0 + P[4]*m1 + P[5]*m2;
    N6 = P[6]*m0 + P[7]*m1 + P[8]*m2; }
  { const float m0=tk[1]*u1, m1=fmaf(tk[4],u1,c1), m2=tk[7]*u1;
    N1 = P[0]*m0 + P[1]*m1 + P[2]*m2;
    N4 = P[3]*m0 + P[4]*m1 + P[5]*m2;
    N7 = P[6]*m0 + P[7]*m1 + P[8]*m2; }
  { const float m0=tk[2]*u2, m1=tk[5]*u2, m2=fmaf(tk[8],u2,c1);
    N2 = P[0]*m0 + P[1]*m1 + P[2]*m2;
    N5 = P[3]*m0 + P[4]*m1 + P[5]*m2;
    N8 = P[6]*m0 + P[7]*m1 + P[8]*m2; }
  P[0]=N0; P[1]=N1; P[2]=N2; P[3]=N3; P[4]=N4;
  P[5]=N5; P[6]=N6; P[7]=N7; P[8]=N8;
}

__device__ __forceinline__ void renorm3(float* __restrict__ P, float& scale){
  float m = P[0];
  #pragma unroll
  for (int e=1;e<9;++e) m = fmaxf(m, P[e]);
  int ex;
  (void)frexpf(m, &ex);
  #pragma unroll
  for (int e=0;e<9;++e) P[e] = ldexpf(P[e], -ex);
  scale += (float)ex;
}

__global__ __launch_bounds__(128) void crf_chunk(
    const float* __restrict__ em, const float* __restrict__ mask,
    const float* __restrict__ trans, const int* __restrict__ tags,
    float* __restrict__ ws) {
  __shared__ float s_em[2][64*EM_ST];
  __shared__ float s_mk[2][64*MK_ST];
  __shared__ int   s_tg[2][64*TG_ST];

  const int lane = threadIdx.x & 63;
  const int wid  = threadIdx.x >> 6;
  const int sg   = blockIdx.x & 63;    // 64 groups of 128 seqs
  const int c    = blockIdx.x >> 6;    // 8 chunks
  const int seqbase = sg*128 + wid*64;
  const int seq = seqbase + lane;
  const bool c0 = (c == 0);

  float* emL = s_em[wid];
  float* mkL = s_mk[wid];
  int*   tgL = s_tg[wid];

  float T2[9], tk[9];
  #pragma unroll
  for (int e=0;e<9;++e){ T2[e] = trans[e]*LOG2E; tk[e] = fexp2(T2[e]); }

  const float4* em4 = (const float4*)em;
  const float4* mk4 = (const float4*)mask;
  const int4*   tg4 = (const int4*)tags;

  // per-u invariants: coalesced f4 index K=64u+lane covers seq-row r=K/3,
  // f4-col=K%3 of each subtile stripe (192 f4 == 64 rows x 3 cols exactly).
  int wa0, wa1, wa2; size_t gb0, gb1, gb2;
  {
    int K, r, col;
    K = lane;        r = K/3; col = K-3*r; wa0 = r*EM_ST+col*4; gb0 = (size_t)(seqbase+r)*768 + (size_t)c*96 + col;
    K = 64 + lane;   r = K/3; col = K-3*r; wa1 = r*EM_ST+col*4; gb1 = (size_t)(seqbase+r)*768 + (size_t)c*96 + col;
    K = 128 + lane;  r = K/3; col = K-3*r; wa2 = r*EM_ST+col*4; gb2 = (size_t)(seqbase+r)*768 + (size_t)c*96 + col;
  }
  const size_t mb = (size_t)seq*256 + (size_t)c*32;

  // prologue: load subtile 0
  float4 sA = em4[gb0], sBv = em4[gb1], sC = em4[gb2];
  float4 sM = mk4[mb];
  int4   sT = tg4[mb];

  float P[9] = {1.f,0.f,0.f, 0.f,1.f,0.f, 0.f,0.f,1.f};
  float scale = 0.f, gold = 0.f;
  float a0 = 0.f, a1 = 0.f, a2 = 0.f, m0s = 0.f;
  int tag0 = 0, prev = 0;

  for (int sub = 0; sub < NSUB; ++sub) {
    // ---- stage current subtile regs -> padded LDS (b64, 2-4-way ~free) ----
    { float2* w = (float2*)&emL[wa0]; w[0]=make_float2(sA.x,sA.y);  w[1]=make_float2(sA.z,sA.w); }
    { float2* w = (float2*)&emL[wa1]; w[0]=make_float2(sBv.x,sBv.y);w[1]=make_float2(sBv.z,sBv.w); }
    { float2* w = (float2*)&emL[wa2]; w[0]=make_float2(sC.x,sC.y);  w[1]=make_float2(sC.z,sC.w); }
    { float2* w = (float2*)&mkL[lane*MK_ST]; w[0]=make_float2(sM.x,sM.y); w[1]=make_float2(sM.z,sM.w); }
    { int2*   w = (int2*)&tgL[lane*TG_ST];   w[0]=make_int2(sT.x,sT.y);   w[1]=make_int2(sT.z,sT.w); }

    // ---- issue next subtile's coalesced loads (in flight during compute) ----
    if (sub + 1 < NSUB) {
      const int o = (sub+1)*3;
      sA = em4[gb0 + o]; sBv = em4[gb1 + o]; sC = em4[gb2 + o];
      sM = mk4[mb + sub + 1];
      sT = tg4[mb + sub + 1];
    }

    // ---- compute 4 steps (2 pairs) from own seq-row in LDS ----
    const float2* ep = (const float2*)&emL[lane*EM_ST];
    const float2* mp = (const float2*)&mkL[lane*MK_ST];
    const int2*   tp = (const int2*)&tgL[lane*TG_ST];
    #pragma unroll
    for (int p = 0; p < 2; ++p) {
      const float2 ea = ep[3*p], eb = ep[3*p+1], ec = ep[3*p+2];
      const float2 mm = mp[p];
      const int2   tt = tp[p];
      #pragma unroll
      for (int jj = 0; jj < 2; ++jj) {
        const float ev0 = (jj ? eb.y : ea.x) * LOG2E;
        const float ev1 = (jj ? ec.x : ea.y) * LOG2E;
        const float ev2 = (jj ? ec.y : eb.x) * LOG2E;
        const float m   = jj ? mm.y : mm.x;
        const int   cur = jj ? tt.y : tt.x;
        const bool first = (sub == 0) && (p == 0) && (jj == 0);

        // gold (log2 domain); chunk-first transition deferred to kernel B
        const float e = mux3(ev0, ev1, ev2, cur);
        if (first) { tag0 = cur; m0s = m; gold = e * m; }
        else       gold = fmaf(trmux(T2, prev, cur) + e, m, gold);
        prev = cur;

        const float w0 = fexp2(ev0), w1 = fexp2(ev1), w2 = fexp2(ev2);
        if (first && c0) { a0 = w0; a1 = w1; a2 = w2; }
        const bool act = (m > 0.f) && !(first && c0);   // t=0 is alpha0
        stepP(P, tk, w0, w1, w2, act ? 1.f : 0.f);
      }
    }
    if (sub & 1) renorm3(P, scale);   // every 8 steps
  }

  // ---- write chunk fields, field-major [c][f][8192] (B reads coalesced) ----
  float* f = ws + (size_t)c*NF*8192 + seq;
  f[0*8192]=P[0]; f[1*8192]=P[1]; f[2*8192]=P[2];
  f[3*8192]=P[3]; f[4*8192]=P[4]; f[5*8192]=P[5];
  f[6*8192]=P[6]; f[7*8192]=P[7]; f[8*8192]=P[8];
  f[9*8192]=scale; f[10*8192]=gold; f[11*8192]=m0s;
  f[12*8192]=(float)(tag0 + 4*prev);
  if (c0) {
    float* aw = ws + (size_t)NF*NCHUNK*8192;
    aw[seq] = a0; aw[8192+seq] = a1; aw[2*8192+seq] = a2;
  }
}

__global__ __launch_bounds__(256) void crf_combine(
    const float* __restrict__ trans, const float* __restrict__ ws,
    float* __restrict__ out) {
  __shared__ float red[4];
  const int seq = blockIdx.x*256 + threadIdx.x;

  float T2[9];
  #pragma unroll
  for (int e=0;e<9;++e) T2[e] = trans[e]*LOG2E;

  const float* aw = ws + (size_t)NF*NCHUNK*8192;
  float al0 = aw[seq], al1 = aw[8192+seq], al2 = aw[2*8192+seq];
  float sc = 0.f, gold = 0.f;
  int lastTag = 0;

  for (int c = 0; c < NCHUNK; ++c) {
    const float* f = ws + (size_t)c*NF*8192 + seq;
    const float p0=f[0*8192], p1=f[1*8192], p2=f[2*8192];
    const float p3=f[3*8192], p4=f[4*8192], p5=f[5*8192];
    const float p6=f[6*8192], p7=f[7*8192], p8=f[8*8192];
    const float csc=f[9*8192], gp=f[10*8192], m0=f[11*8192];
    const int tp = (int)f[12*8192];
    const int t0 = tp & 3, tl = tp >> 2;

    gold += gp + (c > 0 ? trmux(T2, lastTag, t0) * m0 : 0.f);
    lastTag = tl;

    const float n0 = al0*p0 + al1*p3 + al2*p6;   // row-vec . P
    const float n1 = al0*p1 + al1*p4 + al2*p7;
    const float n2 = al0*p2 + al1*p5 + al2*p8;
    float mx = fmaxf(n0, fmaxf(n1, n2));
    int ex; (void)frexpf(mx, &ex);
    al0 = ldexpf(n0, -ex); al1 = ldexpf(n1, -ex); al2 = ldexpf(n2, -ex);
    sc += csc + (float)ex;
  }

  const float z = al0 + al1 + al2;
  float v = LN2 * (sc + flog2(z) - gold);
  #pragma unroll
  for (int d = 1; d < 64; d <<= 1) v += __shfl_xor(v, d, 64);
  if ((threadIdx.x & 63) == 0) red[threadIdx.x >> 6] = v;
  __syncthreads();
  if (threadIdx.x == 0)
    atomicAdd(out, (red[0]+red[1]+red[2]+red[3]) * (1.0f/(float)B));
}

extern "C" void kernel_launch(void* const* d_in, const int* in_sizes, int n_in,
                              void* d_out, int out_size, void* d_ws, size_t ws_size,
                              hipStream_t stream) {
  const float* em    = (const float*)d_in[0];
  const float* mask  = (const float*)d_in[1];
  const float* trans = (const float*)d_in[2];
  const int*   tags  = (const int*)d_in[3];
  float* out = (float*)d_out;
  float* ws  = (float*)d_ws;   // (13*8 + 3) * 8192 floats = 3.44 MB

  hipMemsetAsync(out, 0, sizeof(float), stream);
  crf_chunk<<<64*NCHUNK, 128, 0, stream>>>(em, mask, trans, tags, ws);
  crf_combine<<<B/256, 256, 0, stream>>>(trans, ws, out);
}

// Round 8
// 203.410 us; speedup vs baseline: 1.1251x; 1.1251x over previous
//
#include <hip/hip_runtime.h>

// LinearCRF: mean_b( logZ_b - gold_b ), B=8192, L=1024, S=3.
// R8: lane=seq chunk scan (R7 structure, first no-spill) + line-exact
// cooperative tiles + 2x occupancy.
//   Kernel A: 2048 wave-chunks (128 seq-groups x 16 chunks of 64 steps),
//   2 waves/block -> 1024 blocks -> 8 waves/CU (R7 had 4 -> latency-bound).
//   Tile = 64 seqs x 16 steps staged per wave: every global f4 load maps
//   4 consecutive lanes onto one 64B line (lane->row l/4, piece l%4) ->
//   16 full lines/instr (R7's 48B em runs + strided mask/tags fetched
//   281 MB vs 168 MB input). LDS strides 50/18/5 dw -> uniform bank use.
//   Same-wave DS ordering: no barriers. All scalars named (no scratch).
//   Kernel B: chain 16 chunk matrices per seq, boundary gold, reduce.

#define LOG2E 1.4426950408889634f
#define LN2   0.6931471805599453f

constexpr int B = 8192;
constexpr int NCHUNK = 16;   // 64-step chunks
constexpr int NWIN = 4;      // 16-step windows per chunk
constexpr int EM_ST = 50;    // LDS dw/row: 48 em + 2 pad
constexpr int MK_ST = 18;    // 16 mask + 2 pad
constexpr int TG_ST = 5;     // 4 packed-tag dw + 1 pad
constexpr int NF = 13;       // ws fields: P[9], scale, gold, m0, tagpack

__device__ __forceinline__ float fexp2(float x){ return __builtin_amdgcn_exp2f(x); }
__device__ __forceinline__ float flog2(float x){ return __builtin_amdgcn_logf(x); }
__device__ __forceinline__ float mux3(float a,float b,float c,int i){
  return i==0 ? a : (i==1 ? b : c);
}
__device__ __forceinline__ float trmux(const float* __restrict__ T2,int p,int c){
  const float r0 = mux3(T2[0],T2[1],T2[2],c);
  const float r1 = mux3(T2[3],T2[4],T2[5],c);
  const float r2 = mux3(T2[6],T2[7],T2[8],c);
  return mux3(r0,r1,r2,p);
}

// P <- P * M, column-wise; M col j = act ? tk[:,j]*w_j : e_j.
__device__ __forceinline__ void stepP(float* __restrict__ P,
                                      const float* __restrict__ tk,
                                      float w0, float w1, float w2, float g){
  const float c1 = 1.f - g;
  const float u0 = w0*g, u1 = w1*g, u2 = w2*g;
  float N0,N1,N2,N3,N4,N5,N6,N7,N8;
  { const float m0=fmaf(tk[0],u0,c1), m1=tk[3]*u0, m2=tk[6]*u0;
    N0 = P[0]*m0 + P[1]*m1 + P[2]*m2;
    N3 = P[3]*m0 + P[4]*m1 + P[5]*m2;
    N6 = P[6]*m0 + P[7]*m1 + P[8]*m2; }
  { const float m0=tk[1]*u1, m1=fmaf(tk[4],u1,c1), m2=tk[7]*u1;
    N1 = P[0]*m0 + P[1]*m1 + P[2]*m2;
    N4 = P[3]*m0 + P[4]*m1 + P[5]*m2;
    N7 = P[6]*m0 + P[7]*m1 + P[8]*m2; }
  { const float m0=tk[2]*u2, m1=tk[5]*u2, m2=fmaf(tk[8],u2,c1);
    N2 = P[0]*m0 + P[1]*m1 + P[2]*m2;
    N5 = P[3]*m0 + P[4]*m1 + P[5]*m2;
    N8 = P[6]*m0 + P[7]*m1 + P[8]*m2; }
  P[0]=N0; P[1]=N1; P[2]=N2; P[3]=N3; P[4]=N4;
  P[5]=N5; P[6]=N6; P[7]=N7; P[8]=N8;
}

__device__ __forceinline__ void renorm3(float* __restrict__ P, float& scale){
  float m = P[0];
  #pragma unroll
  for (int e=1;e<9;++e) m = fmaxf(m, P[e]);
  int ex;
  (void)frexpf(m, &ex);
  #pragma unroll
  for (int e=0;e<9;++e) P[e] = ldexpf(P[e], -ex);
  scale += (float)ex;
}

__global__ __launch_bounds__(128, 2) void crf_chunk(
    const float* __restrict__ em, const float* __restrict__ mask,
    const float* __restrict__ trans, const int* __restrict__ tags,
    float* __restrict__ ws) {
  __shared__ float    s_em[2][64 * EM_ST];   // 25.0 KB
  __shared__ float    s_mk[2][64 * MK_ST];   //  9.0 KB
  __shared__ unsigned s_tg[2][64 * TG_ST];   //  2.5 KB  -> 36.5 KB/block

  const int lane = threadIdx.x & 63;
  const int wid  = threadIdx.x >> 6;
  const int gw   = blockIdx.x * 2 + wid;     // 0..2047 wave-chunk id
  const int c    = gw & (NCHUNK - 1);
  const int grp  = gw >> 4;                  // 0..127 seq-group
  const bool c0  = (c == 0);
  const int rq = lane >> 2, ri = lane & 3;   // row-in-16-block, 16B piece
  const int seq = grp * 64 + lane;

  float*    Lem = s_em[wid];
  float*    Lmk = s_mk[wid];
  unsigned* Ltg = s_tg[wid];

  float T2[9], tk[9];
  #pragma unroll
  for (int e=0;e<9;++e){ T2[e] = trans[e]*LOG2E; tk[e] = fexp2(T2[e]); }

  const float4* em4 = (const float4*)em;
  const float4* mk4 = (const float4*)mask;
  const int4*   tg4 = (const int4*)tags;

  // line-exact bases: instr (q,g) covers rows 16q+rq, byte piece ri.
  const size_t ebase = (size_t)(grp*64 + rq) * 192 + (size_t)c*48 + ri;
  const size_t mbase = (size_t)(grp*64 + rq) * 256 + (size_t)c*16 + ri;
  const int ewb = 50*rq + 4*ri;   // em LDS write base (dw)
  const int mwb = 18*rq + 4*ri;
  const int twb = 5*rq + ri;

  float P[9] = {1.f,0.f,0.f, 0.f,1.f,0.f, 0.f,0.f,1.f};
  float scale = 0.f, gold = 0.f;
  float a0 = 0.f, a1 = 0.f, a2 = 0.f, m0s = 0.f;
  int tag0 = 0, prev = 0;

  for (int w = 0; w < NWIN; ++w) {
    // ---- 20 coalesced loads: each = 16 full 64B lines ----
    const size_t eb = ebase + 12*w;
    const float4 e00 = em4[eb+0],    e01 = em4[eb+4],    e02 = em4[eb+8];
    const float4 e10 = em4[eb+3072], e11 = em4[eb+3076], e12 = em4[eb+3080];
    const float4 e20 = em4[eb+6144], e21 = em4[eb+6148], e22 = em4[eb+6152];
    const float4 e30 = em4[eb+9216], e31 = em4[eb+9220], e32 = em4[eb+9224];
    const size_t mb = mbase + 4*w;
    const float4 km0 = mk4[mb],      km1 = mk4[mb+4096];
    const float4 km2 = mk4[mb+8192], km3 = mk4[mb+12288];
    const int4   kt0 = tg4[mb],      kt1 = tg4[mb+4096];
    const int4   kt2 = tg4[mb+8192], kt3 = tg4[mb+12288];

    // ---- scatter to padded LDS (b64 pairs; uniform bank groups) ----
    { float2* p=(float2*)&Lem[ewb+  0+ 0]; p[0]=make_float2(e00.x,e00.y); p[1]=make_float2(e00.z,e00.w); }
    { float2* p=(float2*)&Lem[ewb+  0+16]; p[0]=make_float2(e01.x,e01.y); p[1]=make_float2(e01.z,e01.w); }
    { float2* p=(float2*)&Lem[ewb+  0+32]; p[0]=make_float2(e02.x,e02.y); p[1]=make_float2(e02.z,e02.w); }
    { float2* p=(float2*)&Lem[ewb+800+ 0]; p[0]=make_float2(e10.x,e10.y); p[1]=make_float2(e10.z,e10.w); }
    { float2* p=(float2*)&Lem[ewb+800+16]; p[0]=make_float2(e11.x,e11.y); p[1]=make_float2(e11.z,e11.w); }
    { float2* p=(float2*)&Lem[ewb+800+32]; p[0]=make_float2(e12.x,e12.y); p[1]=make_float2(e12.z,e12.w); }
    { float2* p=(float2*)&Lem[ewb+1600+ 0]; p[0]=make_float2(e20.x,e20.y); p[1]=make_float2(e20.z,e20.w); }
    { float2* p=(float2*)&Lem[ewb+1600+16]; p[0]=make_float2(e21.x,e21.y); p[1]=make_float2(e21.z,e21.w); }
    { float2* p=(float2*)&Lem[ewb+1600+32]; p[0]=make_float2(e22.x,e22.y); p[1]=make_float2(e22.z,e22.w); }
    { float2* p=(float2*)&Lem[ewb+2400+ 0]; p[0]=make_float2(e30.x,e30.y); p[1]=make_float2(e30.z,e30.w); }
    { float2* p=(float2*)&Lem[ewb+2400+16]; p[0]=make_float2(e31.x,e31.y); p[1]=make_float2(e31.z,e31.w); }
    { float2* p=(float2*)&Lem[ewb+2400+32]; p[0]=make_float2(e32.x,e32.y); p[1]=make_float2(e32.z,e32.w); }
    { float2* p=(float2*)&Lmk[mwb+  0]; p[0]=make_float2(km0.x,km0.y); p[1]=make_float2(km0.z,km0.w); }
    { float2* p=(float2*)&Lmk[mwb+288]; p[0]=make_float2(km1.x,km1.y); p[1]=make_float2(km1.z,km1.w); }
    { float2* p=(float2*)&Lmk[mwb+576]; p[0]=make_float2(km2.x,km2.y); p[1]=make_float2(km2.z,km2.w); }
    { float2* p=(float2*)&Lmk[mwb+864]; p[0]=make_float2(km3.x,km3.y); p[1]=make_float2(km3.z,km3.w); }
    Ltg[twb+  0] = (unsigned)(kt0.x&3)|((unsigned)(kt0.y&3)<<8)|((unsigned)(kt0.z&3)<<16)|((unsigned)(kt0.w&3)<<24);
    Ltg[twb+ 80] = (unsigned)(kt1.x&3)|((unsigned)(kt1.y&3)<<8)|((unsigned)(kt1.z&3)<<16)|((unsigned)(kt1.w&3)<<24);
    Ltg[twb+160] = (unsigned)(kt2.x&3)|((unsigned)(kt2.y&3)<<8)|((unsigned)(kt2.z&3)<<16)|((unsigned)(kt2.w&3)<<24);
    Ltg[twb+240] = (unsigned)(kt3.x&3)|((unsigned)(kt3.y&3)<<8)|((unsigned)(kt3.z&3)<<16)|((unsigned)(kt3.w&3)<<24);

    // ---- read own seq row + 16 steps (same-wave DS order: no barrier) ----
    const float2* ep = (const float2*)&Lem[lane * EM_ST];
    const float2* mp = (const float2*)&Lmk[lane * MK_ST];
    const unsigned pA = Ltg[lane*TG_ST+0], pB = Ltg[lane*TG_ST+1];
    const unsigned pC = Ltg[lane*TG_ST+2], pD = Ltg[lane*TG_ST+3];

    #pragma unroll
    for (int t = 0; t < 8; ++t) {
      const float2 xa = ep[3*t], xb = ep[3*t+1], xc = ep[3*t+2];
      const float2 mm = mp[t];
      const unsigned pw = (t < 2) ? pA : ((t < 4) ? pB : ((t < 6) ? pC : pD));
      #pragma unroll
      for (int jj = 0; jj < 2; ++jj) {
        const int j = 2*t + jj;
        const float ev0 = (jj ? xb.y : xa.x) * LOG2E;
        const float ev1 = (jj ? xc.x : xa.y) * LOG2E;
        const float ev2 = (jj ? xc.y : xb.x) * LOG2E;
        const float m   = jj ? mm.y : mm.x;
        const int   cur = (int)((pw >> (8*(j&3))) & 3u);
        const bool first = (w == 0) && (t == 0) && (jj == 0);  // wave-uniform

        const float e = mux3(ev0, ev1, ev2, cur);
        if (first) { tag0 = cur; m0s = m; gold = e * m; }
        else       gold = fmaf(trmux(T2, prev, cur) + e, m, gold);
        prev = cur;

        const float w0 = fexp2(ev0), w1 = fexp2(ev1), w2 = fexp2(ev2);
        if (first && c0) { a0 = w0; a1 = w1; a2 = w2; }
        const bool act = (m > 0.f) && !(first && c0);   // t=0 is alpha0
        stepP(P, tk, w0, w1, w2, act ? 1.f : 0.f);
      }
      if (t == 3 || t == 7) renorm3(P, scale);   // every 8 steps
    }
  }

  // ---- write chunk fields, field-major [c][f][8192] ----
  float* f = ws + (size_t)c*NF*8192 + seq;
  f[0*8192]=P[0]; f[1*8192]=P[1]; f[2*8192]=P[2];
  f[3*8192]=P[3]; f[4*8192]=P[4]; f[5*8192]=P[5];
  f[6*8192]=P[6]; f[7*8192]=P[7]; f[8*8192]=P[8];
  f[9*8192]=scale; f[10*8192]=gold; f[11*8192]=m0s;
  f[12*8192]=(float)(tag0 + 4*prev);
  if (c0) {
    float* aw = ws + (size_t)NF*NCHUNK*8192;
    aw[seq] = a0; aw[8192+seq] = a1; aw[2*8192+seq] = a2;
  }
}

__global__ __launch_bounds__(256) void crf_combine(
    const float* __restrict__ trans, const float* __restrict__ ws,
    float* __restrict__ out) {
  __shared__ float red[4];
  const int seq = blockIdx.x*256 + threadIdx.x;

  float T2[9];
  #pragma unroll
  for (int e=0;e<9;++e) T2[e] = trans[e]*LOG2E;

  const float* aw = ws + (size_t)NF*NCHUNK*8192;
  float al0 = aw[seq], al1 = aw[8192+seq], al2 = aw[2*8192+seq];
  float sc = 0.f, gold = 0.f;
  int lastTag = 0;

  for (int c = 0; c < NCHUNK; ++c) {
    const float* f = ws + (size_t)c*NF*8192 + seq;
    const float p0=f[0*8192], p1=f[1*8192], p2=f[2*8192];
    const float p3=f[3*8192], p4=f[4*8192], p5=f[5*8192];
    const float p6=f[6*8192], p7=f[7*8192], p8=f[8*8192];
    const float csc=f[9*8192], gp=f[10*8192], m0=f[11*8192];
    const int tp = (int)f[12*8192];
    const int t0 = tp & 3, tl = tp >> 2;

    gold += gp + (c > 0 ? trmux(T2, lastTag, t0) * m0 : 0.f);
    lastTag = tl;

    const float n0 = al0*p0 + al1*p3 + al2*p6;   // row-vec . P
    const float n1 = al0*p1 + al1*p4 + al2*p7;
    const float n2 = al0*p2 + al1*p5 + al2*p8;
    float mx = fmaxf(n0, fmaxf(n1, n2));
    int ex; (void)frexpf(mx, &ex);
    al0 = ldexpf(n0, -ex); al1 = ldexpf(n1, -ex); al2 = ldexpf(n2, -ex);
    sc += csc + (float)ex;
  }

  const float z = al0 + al1 + al2;
  float v = LN2 * (sc + flog2(z) - gold);
  #pragma unroll
  for (int d = 1; d < 64; d <<= 1) v += __shfl_xor(v, d, 64);
  if ((threadIdx.x & 63) == 0) red[threadIdx.x >> 6] = v;
  __syncthreads();
  if (threadIdx.x == 0)
    atomicAdd(out, (red[0]+red[1]+red[2]+red[3]) * (1.0f/(float)B));
}

extern "C" void kernel_launch(void* const* d_in, const int* in_sizes, int n_in,
                              void* d_out, int out_size, void* d_ws, size_t ws_size,
                              hipStream_t stream) {
  const float* em    = (const float*)d_in[0];
  const float* mask  = (const float*)d_in[1];
  const float* trans = (const float*)d_in[2];
  const int*   tags  = (const int*)d_in[3];
  float* out = (float*)d_out;
  float* ws  = (float*)d_ws;   // (13*16 + 3) * 8192 floats = 6.9 MB

  hipMemsetAsync(out, 0, sizeof(float), stream);
  crf_chunk<<<1024, 128, 0, stream>>>(em, mask, trans, tags, ws);
  crf_combine<<<B/256, 256, 0, stream>>>(trans, ws, out);
}